// Round 3
// baseline (231.686 us; speedup 1.0000x reference)
//
#include <hip/hip_runtime.h>
#include <hip/hip_bf16.h>

// Fused single-head attention, bf16 MFMA path, flash-decoding split-K.
//   x[4,4096,1024] fp32, W_qkv[1024,192], b_qkv[192], W_out[64,1024], b_out[1024]
//   out[4,4096,1024] fp32
// prep (weights->bf16 transposed) -> qkv GEMM (barrier-free direct-to-register
//   fragments, 16 rows/block x 1024 blocks = 4 blocks/CU for TLP latency hiding,
//   Q pre-scaled 1/8, V^T stored as 16-key tiles)
//   -> attn_partial (4 key-splits, no-max softmax, unnormalized O + l)
//   -> combine + out-proj (4-way e-split).

#define LD 72  // LDS row stride in bf16 elems: 144 B, 16B-aligned, 4-bank rotate/row

typedef __attribute__((ext_vector_type(8))) short short8;   // 8 bf16 (MFMA A/B frag)
typedef __attribute__((ext_vector_type(4))) short short4v;  // 4 bf16 (8 B)
typedef __attribute__((ext_vector_type(4))) float floatx4;  // MFMA C/D frag

#define MFMA(a, b, c) __builtin_amdgcn_mfma_f32_16x16x32_bf16((a), (b), (c), 0, 0, 0)

__device__ __forceinline__ unsigned short f2bf(float f) {
  union { float f; unsigned u; } c; c.f = f;
  unsigned u = c.u + 0x7fffu + ((c.u >> 16) & 1u);  // RNE
  return (unsigned short)(u >> 16);
}
__device__ __forceinline__ float asf(unsigned u) {
  union { unsigned u; float f; } c; c.u = u; return c.f;
}

// ---------------- prep: WtQkv[n=192][k=1024] = W_qkv[k][n]; WtOut[e=1024][d=64] = W_out[d][e]
__global__ __launch_bounds__(256) void prep_kernel(
    const float* __restrict__ Wqkv, const float* __restrict__ Wout,
    unsigned short* __restrict__ WtQkv, unsigned short* __restrict__ WtOut) {
  int idx = blockIdx.x * 256 + threadIdx.x;
  if (idx < 192 * 1024) {
    int n = idx >> 10, k = idx & 1023;
    WtQkv[idx] = f2bf(Wqkv[k * 192 + n]);
  } else if (idx < 192 * 1024 + 1024 * 64) {
    int j = idx - 192 * 1024;
    int e = j >> 6, d = j & 63;
    WtOut[j] = f2bf(Wout[d * 1024 + e]);
  }
}

// ---------------- QKV: 16 rows/block, 1024 blocks (4/CU -> 16 waves/CU of TLP).
// Wave w owns a 16x48 output tile: cols 48w..48w+47, acc[3]; NO main-loop LDS/barriers.
// A (x rows, shared by all 4 waves -> L1 hits) and B (W^T cols, L2-resident) are
// loaded straight from global into registers with a one-iteration prefetch.
// Epilogue: LDS stage -> coalesced streams; Q pre-scaled 1/8; V^T 16-key tiles.
__global__ __launch_bounds__(256, 4) void qkv_kernel(
    const float* __restrict__ x, const unsigned short* __restrict__ WtQkv,
    const float* __restrict__ bqkv,
    unsigned short* __restrict__ Qg, unsigned short* __restrict__ Kg,
    unsigned short* __restrict__ Vtg) {
  __shared__ __align__(16) unsigned short eQ[16 * LD];
  __shared__ __align__(16) unsigned short eK[16 * LD];
  __shared__ __align__(16) unsigned short eV[64 * 24];

  const int tid = threadIdx.x;
  const int wave = tid >> 6, lane = tid & 63, quad = lane >> 4, l16 = lane & 15;
  const int row0 = blockIdx.x * 16;
  const int colbase = wave * 48;

  floatx4 acc[3];
#pragma unroll
  for (int t = 0; t < 3; t++) acc[t] = (floatx4)(0.0f);

  // Per-lane fragment pointers (advance 64 k-elems per iteration).
  const float* pA = x + (size_t)(row0 + l16) * 1024 + quad * 8;
  const unsigned short* pB[3];
#pragma unroll
  for (int t = 0; t < 3; t++)
    pB[t] = WtQkv + (size_t)(colbase + t * 16 + l16) * 1024 + quad * 8;

  // Register-prefetched raw data for the current iteration.
  float4 ax[2][2];  // [kh][half]: 8 floats per A-frag
  uint4 bw[3][2];   // [t][kh]: 8 bf16 per B-frag
#pragma unroll
  for (int kh = 0; kh < 2; kh++) {
    ax[kh][0] = *(const float4*)(pA + kh * 32);
    ax[kh][1] = *(const float4*)(pA + kh * 32 + 4);
  }
#pragma unroll
  for (int t = 0; t < 3; t++) {
    bw[t][0] = *(const uint4*)(pB[t]);
    bw[t][1] = *(const uint4*)(pB[t] + 32);
  }

  for (int kc = 0; kc < 16; kc++) {
    // Convert current A data to bf16 fragments.
    short8 af[2];
#pragma unroll
    for (int kh = 0; kh < 2; kh++) {
      const float* f0 = (const float*)&ax[kh][0];
      const float* f1 = (const float*)&ax[kh][1];
      short8 a;
      a[0] = (short)f2bf(f0[0]); a[1] = (short)f2bf(f0[1]);
      a[2] = (short)f2bf(f0[2]); a[3] = (short)f2bf(f0[3]);
      a[4] = (short)f2bf(f1[0]); a[5] = (short)f2bf(f1[1]);
      a[6] = (short)f2bf(f1[2]); a[7] = (short)f2bf(f1[3]);
      af[kh] = a;
    }
    if (kc < 15) {  // prefetch next iteration's A
#pragma unroll
      for (int kh = 0; kh < 2; kh++) {
        ax[kh][0] = *(const float4*)(pA + 64 + kh * 32);
        ax[kh][1] = *(const float4*)(pA + 64 + kh * 32 + 4);
      }
    }
#pragma unroll
    for (int t = 0; t < 3; t++) {
      short8 b0 = __builtin_bit_cast(short8, bw[t][0]);
      short8 b1 = __builtin_bit_cast(short8, bw[t][1]);
      if (kc < 15) {  // prefetch next iteration's B-frags for this t
        bw[t][0] = *(const uint4*)(pB[t] + 64);
        bw[t][1] = *(const uint4*)(pB[t] + 96);
      }
      acc[t] = MFMA(af[0], b0, acc[t]);
      acc[t] = MFMA(af[1], b1, acc[t]);
    }
    pA += 64;
#pragma unroll
    for (int t = 0; t < 3; t++) pB[t] += 64;
  }

  // ---- epilogue: stage into LDS, then coalesced streams ----
  const int b = row0 >> 12, srow = row0 & 4095;
#pragma unroll
  for (int t = 0; t < 3; t++) {
    int col = colbase + t * 16 + l16;
    float bias = bqkv[col];
    int sec = col >> 6, d = col & 63;
#pragma unroll
    for (int r = 0; r < 4; r++) {
      int lrow = quad * 4 + r;  // 0..15 (C layout: row=quad*4+r)
      float v = acc[t][r] + bias;
      if (sec == 0)      eQ[lrow * LD + d] = f2bf(v * 0.125f);
      else if (sec == 1) eK[lrow * LD + d] = f2bf(v);
      else               eV[d * 24 + lrow] = f2bf(v);  // transpose for V
    }
  }
  __syncthreads();
  {  // coalesced streams: Q,K = 2KB contiguous; V = one 2KB 16-key tile
    int r = tid >> 4, sg = tid & 15;  // 8 B per thread
    *(uint2*)(Qg + (size_t)(row0 + r) * 64 + sg * 4) = *(const uint2*)(&eQ[r * LD + sg * 4]);
    *(uint2*)(Kg + (size_t)(row0 + r) * 64 + sg * 4) = *(const uint2*)(&eK[r * LD + sg * 4]);
    int d = tid >> 2, s2 = tid & 3;
    *(uint2*)(Vtg + (((size_t)b * 256 + (srow >> 4)) * 64 + d) * 16 + s2 * 4)
        = *(const uint2*)(&eV[d * 24 + s2 * 4]);
  }
}

// ---------------- attention partial: block = (qtile, batch, key-split); 1024 keys/split.
// No-max online softmax (scores bounded; Q pre-scaled). Outputs unnormalized O (bf16) + l.
// V^T is tiled: VT[b][key/16][d][16].
__global__ __launch_bounds__(256, 4) void attn_kernel(
    const unsigned short* __restrict__ Qg, const unsigned short* __restrict__ Kg,
    const unsigned short* __restrict__ Vtg,
    unsigned short* __restrict__ Opart, float* __restrict__ Lpart) {
  __shared__ __align__(16) unsigned short Ks[64 * LD];
  __shared__ __align__(16) unsigned short Vs[64 * LD];   // [d][key]
  __shared__ __align__(16) unsigned short QP[64 * LD];   // Q stage, then per-wave P strips

  const int tid = threadIdx.x;
  const int wave = tid >> 6, lane = tid & 63, quad = lane >> 4, l16 = lane & 15;
  const int bid = blockIdx.x;
  const int combo = bid & 15, qt = bid >> 4;   // combo fastest: XCD groups (batch,split)
  const int b = combo >> 2, split = combo & 3;
  const int q0 = qt * 64, key0 = split * 1024;

  {  // Q stage — wave-aligned (tid>>2 spans exactly this wave's 16 rows): no barrier needed
    int r = tid >> 2, seg = tid & 3;
    const uint4* s = (const uint4*)(Qg + ((size_t)b * 4096 + q0 + r) * 64 + seg * 16);
    *(uint4*)(&QP[r * LD + seg * 16])     = s[0];
    *(uint4*)(&QP[r * LD + seg * 16 + 8]) = s[1];
  }
  short8 aq0 = *(const short8*)(&QP[(wave * 16 + l16) * LD + quad * 8]);
  short8 aq1 = *(const short8*)(&QP[(wave * 16 + l16) * LD + 32 + quad * 8]);

  floatx4 o[4];
  float lsum[4];
#pragma unroll
  for (int t = 0; t < 4; t++) o[t] = (floatx4)(0.0f);
#pragma unroll
  for (int r = 0; r < 4; r++) lsum[r] = 0.0f;

  const int kr = tid >> 2, kseg = tid & 3;
  const unsigned short* Kbase = Kg + ((size_t)b * 4096 + key0) * 64;
  const unsigned short* Vt0 = Vtg + ((size_t)b * 256 + (key0 >> 4)) * 1024;  // tile=1024 shorts

  uint4 pk0, pk1, pv0, pv1;
  pk0 = *(const uint4*)(Kbase + (size_t)kr * 64 + kseg * 16);
  pk1 = *(const uint4*)(Kbase + (size_t)kr * 64 + kseg * 16 + 8);
  pv0 = *(const uint4*)(Vt0 + ((size_t)kseg * 64 + kr) * 16);
  pv1 = *(const uint4*)(Vt0 + ((size_t)kseg * 64 + kr) * 16 + 8);

  unsigned short* Pw = &QP[wave * 16 * LD];

  for (int kc = 0; kc < 16; kc++) {
    __syncthreads();
    *(uint4*)(&Ks[kr * LD + kseg * 16])     = pk0;
    *(uint4*)(&Ks[kr * LD + kseg * 16 + 8]) = pk1;
    *(uint4*)(&Vs[kr * LD + kseg * 16])     = pv0;
    *(uint4*)(&Vs[kr * LD + kseg * 16 + 8]) = pv1;
    __syncthreads();
    if (kc < 15) {  // register prefetch of next K/V chunk, overlaps compute
      int nk = (kc + 1) * 64;
      int tl = (kc + 1) * 4 + kseg;  // V tile-local index
      pk0 = *(const uint4*)(Kbase + (size_t)(nk + kr) * 64 + kseg * 16);
      pk1 = *(const uint4*)(Kbase + (size_t)(nk + kr) * 64 + kseg * 16 + 8);
      pv0 = *(const uint4*)(Vt0 + ((size_t)tl * 64 + kr) * 16);
      pv1 = *(const uint4*)(Vt0 + ((size_t)tl * 64 + kr) * 16 + 8);
    }

    floatx4 sc[4];
#pragma unroll
    for (int t = 0; t < 4; t++) sc[t] = (floatx4)(0.0f);
#pragma unroll
    for (int t = 0; t < 4; t++) {
      short8 b0 = *(const short8*)(&Ks[(t * 16 + l16) * LD + quad * 8]);
      short8 b1 = *(const short8*)(&Ks[(t * 16 + l16) * LD + 32 + quad * 8]);
      sc[t] = MFMA(aq0, b0, sc[t]);
      sc[t] = MFMA(aq1, b1, sc[t]);
    }

    // p = exp(s): no max subtraction (|s| bounded), no rescale, l accumulates per-lane
#pragma unroll
    for (int r = 0; r < 4; r++) {
#pragma unroll
      for (int t = 0; t < 4; t++) {
        float pv = __expf(sc[t][r]);
        lsum[r] += pv;
        Pw[(quad * 4 + r) * LD + t * 16 + l16] = f2bf(pv);
      }
    }
    short8 ap0 = *(const short8*)(&Pw[l16 * LD + quad * 8]);
    short8 ap1 = *(const short8*)(&Pw[l16 * LD + 32 + quad * 8]);
#pragma unroll
    for (int t = 0; t < 4; t++) {
      short8 b0 = *(const short8*)(&Vs[(t * 16 + l16) * LD + quad * 8]);
      short8 b1 = *(const short8*)(&Vs[(t * 16 + l16) * LD + 32 + quad * 8]);
      o[t] = MFMA(ap0, b0, o[t]);
      o[t] = MFMA(ap1, b1, o[t]);
    }
  }

  // row-sum of l across the 16-lane col group (cols live in l16; rows in quad)
#pragma unroll
  for (int r = 0; r < 4; r++) {
#pragma unroll
    for (int off = 1; off < 16; off <<= 1) lsum[r] += __shfl_xor(lsum[r], off, 64);
  }

  unsigned short* Ob = Opart + ((size_t)bid * 64 + wave * 16) * 64;
#pragma unroll
  for (int t = 0; t < 4; t++)
#pragma unroll
    for (int r = 0; r < 4; r++)
      Ob[(quad * 4 + r) * 64 + t * 16 + l16] = f2bf(o[t][r]);
  if (l16 == 0) {
#pragma unroll
    for (int r = 0; r < 4; r++)
      Lpart[bid * 64 + wave * 16 + quad * 4 + r] = lsum[r];
  }
}

// ---------------- combine partials + fused out-proj; block = (batch, qtile, e-quarter).
__global__ __launch_bounds__(256, 4) void combine_kernel(
    const unsigned short* __restrict__ Opart, const float* __restrict__ Lpart,
    const unsigned short* __restrict__ WtOut, const float* __restrict__ bout,
    float* __restrict__ out) {
  __shared__ __align__(16) unsigned short Cs[4][16 * LD];
  __shared__ __align__(16) unsigned short Wl[128 * LD];

  const int tid = threadIdx.x;
  const int wave = tid >> 6, lane = tid & 63, quad = lane >> 4, l16 = lane & 15;
  const int cid = blockIdx.x;
  const int eq = cid & 3, qt = (cid >> 2) & 63, b = cid >> 8;
  const int e0 = eq * 256;

  // sum 4 partials; lane owns (q = lane>>2, 16 d starting at (lane&3)*16)
  const int q = lane >> 2, d0 = (lane & 3) * 16;
  float accv[16];
#pragma unroll
  for (int i = 0; i < 16; i++) accv[i] = 0.0f;
  float lq = 0.0f;
#pragma unroll
  for (int s = 0; s < 4; s++) {
    int pid = qt * 16 + b * 4 + s;
    const unsigned short* src = Opart + ((size_t)pid * 64 + wave * 16 + q) * 64 + d0;
    uint4 h0 = *(const uint4*)src;
    uint4 h1 = *(const uint4*)(src + 8);
    const unsigned* hw = (const unsigned*)&h0;
#pragma unroll
    for (int i = 0; i < 4; i++) {
      accv[2 * i]     += asf(hw[i] << 16);
      accv[2 * i + 1] += asf(hw[i] & 0xFFFF0000u);
    }
    const unsigned* hw1 = (const unsigned*)&h1;
#pragma unroll
    for (int i = 0; i < 4; i++) {
      accv[8 + 2 * i]     += asf(hw1[i] << 16);
      accv[8 + 2 * i + 1] += asf(hw1[i] & 0xFFFF0000u);
    }
    lq += Lpart[pid * 64 + wave * 16 + q];
  }
  float inv = 1.0f / lq;
  short8 c0, c1;
#pragma unroll
  for (int i = 0; i < 8; i++) {
    c0[i] = (short)f2bf(accv[i] * inv);
    c1[i] = (short)f2bf(accv[8 + i] * inv);
  }
  *(short8*)(&Cs[wave][q * LD + d0])     = c0;
  *(short8*)(&Cs[wave][q * LD + d0 + 8]) = c1;
  // same-wave LDS round-trip (row q written by lane q*4.. of this wave): no barrier
  short8 ao0 = *(const short8*)(&Cs[wave][l16 * LD + quad * 8]);
  short8 ao1 = *(const short8*)(&Cs[wave][l16 * LD + 32 + quad * 8]);

  const size_t orow0 = (size_t)b * 4096 + qt * 64 + wave * 16;
#pragma unroll 1
  for (int ec = 0; ec < 2; ec++) {
    int ebase = e0 + ec * 128;
    __syncthreads();
    {  // stage 128 rows of WtOut: 2 threads/row, 32 elems (64 B) each
      int er = tid >> 1, half = tid & 1;
      const uint4* s = (const uint4*)(WtOut + (size_t)(ebase + er) * 64 + half * 32);
      uint4 w0 = s[0], w1 = s[1], w2 = s[2], w3 = s[3];
      *(uint4*)(&Wl[er * LD + half * 32])      = w0;
      *(uint4*)(&Wl[er * LD + half * 32 + 8])  = w1;
      *(uint4*)(&Wl[er * LD + half * 32 + 16]) = w2;
      *(uint4*)(&Wl[er * LD + half * 32 + 24]) = w3;
    }
    __syncthreads();
    floatx4 a2[8];
#pragma unroll
    for (int t = 0; t < 8; t++) a2[t] = (floatx4)(0.0f);
#pragma unroll
    for (int t = 0; t < 8; t++) {
      short8 b0 = *(const short8*)(&Wl[(t * 16 + l16) * LD + quad * 8]);
      short8 b1 = *(const short8*)(&Wl[(t * 16 + l16) * LD + 32 + quad * 8]);
      a2[t] = MFMA(ao0, b0, a2[t]);
      a2[t] = MFMA(ao1, b1, a2[t]);
    }
#pragma unroll
    for (int t = 0; t < 8; t++) {
      int e = ebase + t * 16 + l16;
      float bo = bout[e];
#pragma unroll
      for (int r = 0; r < 4; r++)
        out[(orow0 + quad * 4 + r) * 1024 + e] = a2[t][r] + bo;
    }
  }
}

extern "C" void kernel_launch(void* const* d_in, const int* in_sizes, int n_in,
                              void* d_out, int out_size, void* d_ws, size_t ws_size,
                              hipStream_t stream) {
  const float* x    = (const float*)d_in[0];  // [4,4096,1024]
  const float* Wqkv = (const float*)d_in[1];  // [1024,192]
  const float* bqkv = (const float*)d_in[2];  // [192]
  const float* Wout = (const float*)d_in[3];  // [64,1024]
  const float* bout = (const float*)d_in[4];  // [1024]
  float* out = (float*)d_out;                 // [4,4096,1024]

  unsigned short* ws = (unsigned short*)d_ws;
  unsigned short* Qg    = ws;                  // 16384*64 (pre-scaled by 1/8)
  unsigned short* Kg    = Qg + 1048576;        // 16384*64
  unsigned short* Vtg   = Kg + 1048576;        // [4][256][64][16] tiled V^T
  unsigned short* WtQkv = Vtg + 1048576;       // [192][1024]
  unsigned short* WtOut = WtQkv + 196608;      // [1024][64]
  unsigned short* Opart = WtOut + 65536;       // [1024][64][64] bf16 unnormalized
  float*          Lpart = (float*)(Opart + 4194304);  // [1024][64]

  prep_kernel<<<1024, 256, 0, stream>>>(Wqkv, Wout, WtQkv, WtOut);
  qkv_kernel<<<1024, 256, 0, stream>>>(x, WtQkv, bqkv, Qg, Kg, Vtg);
  attn_kernel<<<1024, 256, 0, stream>>>(Qg, Kg, Vtg, Opart, Lpart);
  combine_kernel<<<1024, 256, 0, stream>>>(Opart, Lpart, WtOut, bout, out);
}

// Round 4
// 208.459 us; speedup vs baseline: 1.1114x; 1.1114x over previous
//
#include <hip/hip_runtime.h>
#include <hip/hip_bf16.h>

// Fused single-head attention, bf16 MFMA path, flash-decoding split-K.
//   x[4,4096,1024] fp32, W_qkv[1024,192], b_qkv[192], W_out[64,1024], b_out[1024]
//   out[4,4096,1024] fp32
// prep (weights->bf16 transposed) -> qkv GEMM (barrier-free direct-to-register
//   fragments, 32 rows/block x 512 blocks = 2 blocks/CU; round-2 wave tile shape
//   (2 row-subtiles x 3 col-tiles) that the compiler pipelines at VGPR~110;
//   Q pre-scaled 1/8, V^T stored as 16-key tiles)
//   -> attn_partial (4 key-splits, no-max softmax, unnormalized O + l)
//   -> combine + out-proj (4-way e-split).

#define LD 72  // LDS row stride in bf16 elems: 144 B, 16B-aligned, 4-bank rotate/row

typedef __attribute__((ext_vector_type(8))) short short8;   // 8 bf16 (MFMA A/B frag)
typedef __attribute__((ext_vector_type(4))) short short4v;  // 4 bf16 (8 B)
typedef __attribute__((ext_vector_type(4))) float floatx4;  // MFMA C/D frag

#define MFMA(a, b, c) __builtin_amdgcn_mfma_f32_16x16x32_bf16((a), (b), (c), 0, 0, 0)

__device__ __forceinline__ unsigned short f2bf(float f) {
  union { float f; unsigned u; } c; c.f = f;
  unsigned u = c.u + 0x7fffu + ((c.u >> 16) & 1u);  // RNE
  return (unsigned short)(u >> 16);
}
__device__ __forceinline__ float asf(unsigned u) {
  union { unsigned u; float f; } c; c.u = u; return c.f;
}

// ---------------- prep: WtQkv[n=192][k=1024] = W_qkv[k][n]; WtOut[e=1024][d=64] = W_out[d][e]
__global__ __launch_bounds__(256) void prep_kernel(
    const float* __restrict__ Wqkv, const float* __restrict__ Wout,
    unsigned short* __restrict__ WtQkv, unsigned short* __restrict__ WtOut) {
  int idx = blockIdx.x * 256 + threadIdx.x;
  if (idx < 192 * 1024) {
    int n = idx >> 10, k = idx & 1023;
    WtQkv[idx] = f2bf(Wqkv[k * 192 + n]);
  } else if (idx < 192 * 1024 + 1024 * 64) {
    int j = idx - 192 * 1024;
    int e = j >> 6, d = j & 63;
    WtOut[j] = f2bf(Wout[d * 1024 + e]);
  }
}

// ---------------- QKV: 32 rows/block, 512 blocks (2/CU -> 8 waves/CU of TLP).
// Wave w owns a 32x48 tile: rows 0-31, cols 48w..48w+47; acc[2][3].
// NO main-loop LDS/barriers. A (x rows, shared by all 4 waves -> L1 hits) and
// B (W^T cols, L2-resident) load straight to registers, 1-iteration prefetch.
// Epilogue: LDS stage -> coalesced streams; Q pre-scaled 1/8; V^T 16-key tiles.
__global__ __launch_bounds__(256, 2) void qkv_kernel(
    const float* __restrict__ x, const unsigned short* __restrict__ WtQkv,
    const float* __restrict__ bqkv,
    unsigned short* __restrict__ Qg, unsigned short* __restrict__ Kg,
    unsigned short* __restrict__ Vtg) {
  __shared__ __align__(16) unsigned short eQ[32 * LD];
  __shared__ __align__(16) unsigned short eK[32 * LD];
  __shared__ __align__(16) unsigned short eV[64 * 40];

  const int tid = threadIdx.x;
  const int wave = tid >> 6, lane = tid & 63, quad = lane >> 4, l16 = lane & 15;
  const int row0 = blockIdx.x * 32;
  const int colbase = wave * 48;

  floatx4 acc[2][3];
#pragma unroll
  for (int rt = 0; rt < 2; rt++)
#pragma unroll
    for (int t = 0; t < 3; t++) acc[rt][t] = (floatx4)(0.0f);

  // Per-lane fragment base pointers (advance by 64 k-elems per iteration).
  const float* pA0 = x + (size_t)(row0 + l16) * 1024 + quad * 8;
  const float* pA1 = pA0 + 16 * 1024;
  const unsigned short* pB[3];
#pragma unroll
  for (int t = 0; t < 3; t++)
    pB[t] = WtQkv + (size_t)(colbase + t * 16 + l16) * 1024 + quad * 8;

  // Register-prefetched raw data for the current iteration.
  float4 ax[2][2][2];  // [rt][kh][half]: 8 floats per A-frag
  uint4 bw[3][2];      // [t][kh]: 8 bf16 per B-frag
#pragma unroll
  for (int kh = 0; kh < 2; kh++) {
    ax[0][kh][0] = *(const float4*)(pA0 + kh * 32);
    ax[0][kh][1] = *(const float4*)(pA0 + kh * 32 + 4);
    ax[1][kh][0] = *(const float4*)(pA1 + kh * 32);
    ax[1][kh][1] = *(const float4*)(pA1 + kh * 32 + 4);
  }
#pragma unroll
  for (int t = 0; t < 3; t++) {
    bw[t][0] = *(const uint4*)(pB[t]);
    bw[t][1] = *(const uint4*)(pB[t] + 32);
  }

  for (int kc = 0; kc < 16; kc++) {
    // Convert current A data to bf16 fragments.
    short8 af[2][2];
#pragma unroll
    for (int rt = 0; rt < 2; rt++)
#pragma unroll
      for (int kh = 0; kh < 2; kh++) {
        const float* f0 = (const float*)&ax[rt][kh][0];
        const float* f1 = (const float*)&ax[rt][kh][1];
        short8 a;
        a[0] = (short)f2bf(f0[0]); a[1] = (short)f2bf(f0[1]);
        a[2] = (short)f2bf(f0[2]); a[3] = (short)f2bf(f0[3]);
        a[4] = (short)f2bf(f1[0]); a[5] = (short)f2bf(f1[1]);
        a[6] = (short)f2bf(f1[2]); a[7] = (short)f2bf(f1[3]);
        af[rt][kh] = a;
      }
    // Prefetch next iteration's A.
    if (kc < 15) {
#pragma unroll
      for (int kh = 0; kh < 2; kh++) {
        ax[0][kh][0] = *(const float4*)(pA0 + 64 + kh * 32);
        ax[0][kh][1] = *(const float4*)(pA0 + 64 + kh * 32 + 4);
        ax[1][kh][0] = *(const float4*)(pA1 + 64 + kh * 32);
        ax[1][kh][1] = *(const float4*)(pA1 + 64 + kh * 32 + 4);
      }
    }
#pragma unroll
    for (int t = 0; t < 3; t++) {
      short8 b0 = __builtin_bit_cast(short8, bw[t][0]);
      short8 b1 = __builtin_bit_cast(short8, bw[t][1]);
      if (kc < 15) {  // prefetch next iteration's B-frags for this t
        bw[t][0] = *(const uint4*)(pB[t] + 64);
        bw[t][1] = *(const uint4*)(pB[t] + 96);
      }
#pragma unroll
      for (int rt = 0; rt < 2; rt++) {
        acc[rt][t] = MFMA(af[rt][0], b0, acc[rt][t]);
        acc[rt][t] = MFMA(af[rt][1], b1, acc[rt][t]);
      }
    }
    pA0 += 64; pA1 += 64;
#pragma unroll
    for (int t = 0; t < 3; t++) pB[t] += 64;
  }

  // ---- epilogue: stage per-wave tiles into LDS, then coalesced streams ----
  const int b = row0 >> 12, srow = row0 & 4095;
#pragma unroll
  for (int rt = 0; rt < 2; rt++)
#pragma unroll
    for (int t = 0; t < 3; t++) {
      int col = colbase + t * 16 + l16;
      float bias = bqkv[col];
      int sec = col >> 6, d = col & 63;
#pragma unroll
      for (int r = 0; r < 4; r++) {
        int lrow = rt * 16 + quad * 4 + r;  // 0..31
        float v = acc[rt][t][r] + bias;
        if (sec == 0)      eQ[lrow * LD + d] = f2bf(v * 0.125f);
        else if (sec == 1) eK[lrow * LD + d] = f2bf(v);
        else               eV[d * 40 + lrow] = f2bf(v);  // transpose for V
      }
    }
  __syncthreads();
  {  // coalesced streams: Q,K = 4KB contiguous; V = two 2KB 16-key tiles
    int r = tid >> 3, sg = tid & 7;  // 32 rows x 8 segs of 16 B
    *(uint4*)(Qg + (size_t)(row0 + r) * 64 + sg * 8) = *(const uint4*)(&eQ[r * LD + sg * 8]);
    *(uint4*)(Kg + (size_t)(row0 + r) * 64 + sg * 8) = *(const uint4*)(&eK[r * LD + sg * 8]);
    int tile = tid >> 7, rem = tid & 127, d = rem >> 1, half = rem & 1;
    *(uint4*)(Vtg + (((size_t)b * 256 + (srow >> 4) + tile) * 64 + d) * 16 + half * 8)
        = *(const uint4*)(&eV[d * 40 + tile * 16 + half * 8]);
  }
}

// ---------------- attention partial: block = (qtile, batch, key-split); 1024 keys/split.
// No-max online softmax (scores bounded; Q pre-scaled). Outputs unnormalized O (bf16) + l.
// V^T is tiled: VT[b][key/16][d][16].
__global__ __launch_bounds__(256, 4) void attn_kernel(
    const unsigned short* __restrict__ Qg, const unsigned short* __restrict__ Kg,
    const unsigned short* __restrict__ Vtg,
    unsigned short* __restrict__ Opart, float* __restrict__ Lpart) {
  __shared__ __align__(16) unsigned short Ks[64 * LD];
  __shared__ __align__(16) unsigned short Vs[64 * LD];   // [d][key]
  __shared__ __align__(16) unsigned short QP[64 * LD];   // Q stage, then per-wave P strips

  const int tid = threadIdx.x;
  const int wave = tid >> 6, lane = tid & 63, quad = lane >> 4, l16 = lane & 15;
  const int bid = blockIdx.x;
  const int combo = bid & 15, qt = bid >> 4;   // combo fastest: XCD groups (batch,split)
  const int b = combo >> 2, split = combo & 3;
  const int q0 = qt * 64, key0 = split * 1024;

  {  // Q stage — wave-aligned (tid>>2 spans exactly this wave's 16 rows): no barrier needed
    int r = tid >> 2, seg = tid & 3;
    const uint4* s = (const uint4*)(Qg + ((size_t)b * 4096 + q0 + r) * 64 + seg * 16);
    *(uint4*)(&QP[r * LD + seg * 16])     = s[0];
    *(uint4*)(&QP[r * LD + seg * 16 + 8]) = s[1];
  }
  short8 aq0 = *(const short8*)(&QP[(wave * 16 + l16) * LD + quad * 8]);
  short8 aq1 = *(const short8*)(&QP[(wave * 16 + l16) * LD + 32 + quad * 8]);

  floatx4 o[4];
  float lsum[4];
#pragma unroll
  for (int t = 0; t < 4; t++) o[t] = (floatx4)(0.0f);
#pragma unroll
  for (int r = 0; r < 4; r++) lsum[r] = 0.0f;

  const int kr = tid >> 2, kseg = tid & 3;
  const unsigned short* Kbase = Kg + ((size_t)b * 4096 + key0) * 64;
  const unsigned short* Vt0 = Vtg + ((size_t)b * 256 + (key0 >> 4)) * 1024;  // tile=1024 shorts

  uint4 pk0, pk1, pv0, pv1;
  pk0 = *(const uint4*)(Kbase + (size_t)kr * 64 + kseg * 16);
  pk1 = *(const uint4*)(Kbase + (size_t)kr * 64 + kseg * 16 + 8);
  pv0 = *(const uint4*)(Vt0 + ((size_t)kseg * 64 + kr) * 16);
  pv1 = *(const uint4*)(Vt0 + ((size_t)kseg * 64 + kr) * 16 + 8);

  unsigned short* Pw = &QP[wave * 16 * LD];

  for (int kc = 0; kc < 16; kc++) {
    __syncthreads();
    *(uint4*)(&Ks[kr * LD + kseg * 16])     = pk0;
    *(uint4*)(&Ks[kr * LD + kseg * 16 + 8]) = pk1;
    *(uint4*)(&Vs[kr * LD + kseg * 16])     = pv0;
    *(uint4*)(&Vs[kr * LD + kseg * 16 + 8]) = pv1;
    __syncthreads();
    if (kc < 15) {  // register prefetch of next K/V chunk, overlaps compute
      int nk = (kc + 1) * 64;
      int tl = (kc + 1) * 4 + kseg;  // V tile-local index
      pk0 = *(const uint4*)(Kbase + (size_t)(nk + kr) * 64 + kseg * 16);
      pk1 = *(const uint4*)(Kbase + (size_t)(nk + kr) * 64 + kseg * 16 + 8);
      pv0 = *(const uint4*)(Vt0 + ((size_t)tl * 64 + kr) * 16);
      pv1 = *(const uint4*)(Vt0 + ((size_t)tl * 64 + kr) * 16 + 8);
    }

    floatx4 sc[4];
#pragma unroll
    for (int t = 0; t < 4; t++) sc[t] = (floatx4)(0.0f);
#pragma unroll
    for (int t = 0; t < 4; t++) {
      short8 b0 = *(const short8*)(&Ks[(t * 16 + l16) * LD + quad * 8]);
      short8 b1 = *(const short8*)(&Ks[(t * 16 + l16) * LD + 32 + quad * 8]);
      sc[t] = MFMA(aq0, b0, sc[t]);
      sc[t] = MFMA(aq1, b1, sc[t]);
    }

    // p = exp(s): no max subtraction (|s| bounded), no rescale, l accumulates per-lane
#pragma unroll
    for (int r = 0; r < 4; r++) {
#pragma unroll
      for (int t = 0; t < 4; t++) {
        float pv = __expf(sc[t][r]);
        lsum[r] += pv;
        Pw[(quad * 4 + r) * LD + t * 16 + l16] = f2bf(pv);
      }
    }
    short8 ap0 = *(const short8*)(&Pw[l16 * LD + quad * 8]);
    short8 ap1 = *(const short8*)(&Pw[l16 * LD + 32 + quad * 8]);
#pragma unroll
    for (int t = 0; t < 4; t++) {
      short8 b0 = *(const short8*)(&Vs[(t * 16 + l16) * LD + quad * 8]);
      short8 b1 = *(const short8*)(&Vs[(t * 16 + l16) * LD + 32 + quad * 8]);
      o[t] = MFMA(ap0, b0, o[t]);
      o[t] = MFMA(ap1, b1, o[t]);
    }
  }

  // row-sum of l across the 16-lane col group (cols live in l16; rows in quad)
#pragma unroll
  for (int r = 0; r < 4; r++) {
#pragma unroll
    for (int off = 1; off < 16; off <<= 1) lsum[r] += __shfl_xor(lsum[r], off, 64);
  }

  unsigned short* Ob = Opart + ((size_t)bid * 64 + wave * 16) * 64;
#pragma unroll
  for (int t = 0; t < 4; t++)
#pragma unroll
    for (int r = 0; r < 4; r++)
      Ob[(quad * 4 + r) * 64 + t * 16 + l16] = f2bf(o[t][r]);
  if (l16 == 0) {
#pragma unroll
    for (int r = 0; r < 4; r++)
      Lpart[bid * 64 + wave * 16 + quad * 4 + r] = lsum[r];
  }
}

// ---------------- combine partials + fused out-proj; block = (batch, qtile, e-quarter).
__global__ __launch_bounds__(256, 4) void combine_kernel(
    const unsigned short* __restrict__ Opart, const float* __restrict__ Lpart,
    const unsigned short* __restrict__ WtOut, const float* __restrict__ bout,
    float* __restrict__ out) {
  __shared__ __align__(16) unsigned short Cs[4][16 * LD];
  __shared__ __align__(16) unsigned short Wl[128 * LD];

  const int tid = threadIdx.x;
  const int wave = tid >> 6, lane = tid & 63, quad = lane >> 4, l16 = lane & 15;
  const int cid = blockIdx.x;
  const int eq = cid & 3, qt = (cid >> 2) & 63, b = cid >> 8;
  const int e0 = eq * 256;

  // sum 4 partials; lane owns (q = lane>>2, 16 d starting at (lane&3)*16)
  const int q = lane >> 2, d0 = (lane & 3) * 16;
  float accv[16];
#pragma unroll
  for (int i = 0; i < 16; i++) accv[i] = 0.0f;
  float lq = 0.0f;
#pragma unroll
  for (int s = 0; s < 4; s++) {
    int pid = qt * 16 + b * 4 + s;
    const unsigned short* src = Opart + ((size_t)pid * 64 + wave * 16 + q) * 64 + d0;
    uint4 h0 = *(const uint4*)src;
    uint4 h1 = *(const uint4*)(src + 8);
    const unsigned* hw = (const unsigned*)&h0;
#pragma unroll
    for (int i = 0; i < 4; i++) {
      accv[2 * i]     += asf(hw[i] << 16);
      accv[2 * i + 1] += asf(hw[i] & 0xFFFF0000u);
    }
    const unsigned* hw1 = (const unsigned*)&h1;
#pragma unroll
    for (int i = 0; i < 4; i++) {
      accv[8 + 2 * i]     += asf(hw1[i] << 16);
      accv[8 + 2 * i + 1] += asf(hw1[i] & 0xFFFF0000u);
    }
    lq += Lpart[pid * 64 + wave * 16 + q];
  }
  float inv = 1.0f / lq;
  short8 c0, c1;
#pragma unroll
  for (int i = 0; i < 8; i++) {
    c0[i] = (short)f2bf(accv[i] * inv);
    c1[i] = (short)f2bf(accv[8 + i] * inv);
  }
  *(short8*)(&Cs[wave][q * LD + d0])     = c0;
  *(short8*)(&Cs[wave][q * LD + d0 + 8]) = c1;
  // same-wave LDS round-trip (row q written by lane q*4.. of this wave): no barrier
  short8 ao0 = *(const short8*)(&Cs[wave][l16 * LD + quad * 8]);
  short8 ao1 = *(const short8*)(&Cs[wave][l16 * LD + 32 + quad * 8]);

  const size_t orow0 = (size_t)b * 4096 + qt * 64 + wave * 16;
#pragma unroll 1
  for (int ec = 0; ec < 2; ec++) {
    int ebase = e0 + ec * 128;
    __syncthreads();
    {  // stage 128 rows of WtOut: 2 threads/row, 32 elems (64 B) each
      int er = tid >> 1, half = tid & 1;
      const uint4* s = (const uint4*)(WtOut + (size_t)(ebase + er) * 64 + half * 32);
      uint4 w0 = s[0], w1 = s[1], w2 = s[2], w3 = s[3];
      *(uint4*)(&Wl[er * LD + half * 32])      = w0;
      *(uint4*)(&Wl[er * LD + half * 32 + 8])  = w1;
      *(uint4*)(&Wl[er * LD + half * 32 + 16]) = w2;
      *(uint4*)(&Wl[er * LD + half * 32 + 24]) = w3;
    }
    __syncthreads();
    floatx4 a2[8];
#pragma unroll
    for (int t = 0; t < 8; t++) a2[t] = (floatx4)(0.0f);
#pragma unroll
    for (int t = 0; t < 8; t++) {
      short8 b0 = *(const short8*)(&Wl[(t * 16 + l16) * LD + quad * 8]);
      short8 b1 = *(const short8*)(&Wl[(t * 16 + l16) * LD + 32 + quad * 8]);
      a2[t] = MFMA(ao0, b0, a2[t]);
      a2[t] = MFMA(ao1, b1, a2[t]);
    }
#pragma unroll
    for (int t = 0; t < 8; t++) {
      int e = ebase + t * 16 + l16;
      float bo = bout[e];
#pragma unroll
      for (int r = 0; r < 4; r++)
        out[(orow0 + quad * 4 + r) * 1024 + e] = a2[t][r] + bo;
    }
  }
}

extern "C" void kernel_launch(void* const* d_in, const int* in_sizes, int n_in,
                              void* d_out, int out_size, void* d_ws, size_t ws_size,
                              hipStream_t stream) {
  const float* x    = (const float*)d_in[0];  // [4,4096,1024]
  const float* Wqkv = (const float*)d_in[1];  // [1024,192]
  const float* bqkv = (const float*)d_in[2];  // [192]
  const float* Wout = (const float*)d_in[3];  // [64,1024]
  const float* bout = (const float*)d_in[4];  // [1024]
  float* out = (float*)d_out;                 // [4,4096,1024]

  unsigned short* ws = (unsigned short*)d_ws;
  unsigned short* Qg    = ws;                  // 16384*64 (pre-scaled by 1/8)
  unsigned short* Kg    = Qg + 1048576;        // 16384*64
  unsigned short* Vtg   = Kg + 1048576;        // [4][256][64][16] tiled V^T
  unsigned short* WtQkv = Vtg + 1048576;       // [192][1024]
  unsigned short* WtOut = WtQkv + 196608;      // [1024][64]
  unsigned short* Opart = WtOut + 65536;       // [1024][64][64] bf16 unnormalized
  float*          Lpart = (float*)(Opart + 4194304);  // [1024][64]

  prep_kernel<<<1024, 256, 0, stream>>>(Wqkv, Wout, WtQkv, WtOut);
  qkv_kernel<<<512, 256, 0, stream>>>(x, WtQkv, bqkv, Qg, Kg, Vtg);
  attn_kernel<<<1024, 256, 0, stream>>>(Qg, Kg, Vtg, Opart, Lpart);
  combine_kernel<<<1024, 256, 0, stream>>>(Opart, Lpart, WtOut, bout, out);
}

// Round 5
// 184.384 us; speedup vs baseline: 1.2565x; 1.1306x over previous
//
#include <hip/hip_runtime.h>
#include <hip/hip_bf16.h>

// Fused single-head attention, bf16 MFMA path, flash-decoding split-K.
//   x[4,4096,1024] fp32, W_qkv[1024,192], b_qkv[192], W_out[64,1024], b_out[1024]
//   out[4,4096,1024] fp32
// prep (weights->bf16 transposed) -> qkv GEMM (LDS double-buffer, ONE barrier per
//   K-step, early-issued register loads -> cast -> LDS write; 32 rows/block x 512
//   blocks = 2 blocks/CU; Q pre-scaled 1/8, V^T stored as 16-key tiles)
//   -> attn_partial (4 key-splits, no-max softmax, unnormalized O + l)
//   -> combine + out-proj (4-way e-split).

#define LD 72  // LDS row stride in bf16 elems: 144 B, 16B-aligned, 4-bank rotate/row

typedef __attribute__((ext_vector_type(8))) short short8;   // 8 bf16 (MFMA A/B frag)
typedef __attribute__((ext_vector_type(4))) short short4v;  // 4 bf16 (8 B)
typedef __attribute__((ext_vector_type(4))) float floatx4;  // MFMA C/D frag

#define MFMA(a, b, c) __builtin_amdgcn_mfma_f32_16x16x32_bf16((a), (b), (c), 0, 0, 0)

__device__ __forceinline__ unsigned short f2bf(float f) {
  union { float f; unsigned u; } c; c.f = f;
  unsigned u = c.u + 0x7fffu + ((c.u >> 16) & 1u);  // RNE
  return (unsigned short)(u >> 16);
}
__device__ __forceinline__ float asf(unsigned u) {
  union { unsigned u; float f; } c; c.u = u; return c.f;
}

// ---------------- prep: WtQkv[n=192][k=1024] = W_qkv[k][n]; WtOut[e=1024][d=64] = W_out[d][e]
__global__ __launch_bounds__(256) void prep_kernel(
    const float* __restrict__ Wqkv, const float* __restrict__ Wout,
    unsigned short* __restrict__ WtQkv, unsigned short* __restrict__ WtOut) {
  int idx = blockIdx.x * 256 + threadIdx.x;
  if (idx < 192 * 1024) {
    int n = idx >> 10, k = idx & 1023;
    WtQkv[idx] = f2bf(Wqkv[k * 192 + n]);
  } else if (idx < 192 * 1024 + 1024 * 64) {
    int j = idx - 192 * 1024;
    int e = j >> 6, d = j & 63;
    WtOut[j] = f2bf(Wout[d * 1024 + e]);
  }
}

// ---------------- QKV: 32 rows/block, 512 blocks (2/CU), LDS double-buffer,
// ONE __syncthreads per K-step. Per step each thread early-issues:
//   x: 2x float4 (32B of one row)  -> cast to 8 bf16 -> 1 ds_write_b128
//   W: 6x uint4 (L2-hot W^T rows)  -> 6 ds_write_b128
// Wave w computes a 32x48 tile (acc[2][3], 12 MFMA/step) from the other buffer.
// Latency of the early loads is covered by the compute phase + 2-block overlap.
// Epilogue (aliased onto staging LDS): Q pre-scaled 1/8; V^T 16-key tiles.
__global__ __launch_bounds__(256, 2) void qkv_kernel(
    const float* __restrict__ x, const unsigned short* __restrict__ WtQkv,
    const float* __restrict__ bqkv,
    unsigned short* __restrict__ Qg, unsigned short* __restrict__ Kg,
    unsigned short* __restrict__ Vtg) {
  __shared__ __align__(16) unsigned short XS[2][32 * LD];   //  9.2 KB
  __shared__ __align__(16) unsigned short WS[2][192 * LD];  // 55.3 KB

  const int tid = threadIdx.x;
  const int wave = tid >> 6, lane = tid & 63, quad = lane >> 4, l16 = lane & 15;
  const int row0 = blockIdx.x * 32;
  const int colbase = wave * 48;

  floatx4 acc[2][3];
#pragma unroll
  for (int rt = 0; rt < 2; rt++)
#pragma unroll
    for (int t = 0; t < 3; t++) acc[rt][t] = (floatx4)(0.0f);

  // Staging map: thread -> x row xr, 16B-chunk xj; W rows xr+32i (i<6), chunk xj.
  const int xr = tid >> 3, xj = tid & 7;
  const float* gx = x + (size_t)(row0 + xr) * 1024 + xj * 8;
  const unsigned short* gw = WtQkv + (size_t)xr * 1024 + xj * 8;

  {  // prologue: stage step 0 into buffer 0
    float4 xa = *(const float4*)(gx);
    float4 xb = *(const float4*)(gx + 4);
    uint4 wv[6];
#pragma unroll
    for (int i = 0; i < 6; i++) wv[i] = *(const uint4*)(gw + i * 32768);
    short8 xc;
    xc[0] = (short)f2bf(xa.x); xc[1] = (short)f2bf(xa.y);
    xc[2] = (short)f2bf(xa.z); xc[3] = (short)f2bf(xa.w);
    xc[4] = (short)f2bf(xb.x); xc[5] = (short)f2bf(xb.y);
    xc[6] = (short)f2bf(xb.z); xc[7] = (short)f2bf(xb.w);
    *(short8*)(&XS[0][xr * LD + xj * 8]) = xc;
#pragma unroll
    for (int i = 0; i < 6; i++)
      *(uint4*)(&WS[0][(xr + 32 * i) * LD + xj * 8]) = wv[i];
  }
  __syncthreads();

  for (int kc = 0; kc < 16; kc++) {
    const int buf = kc & 1;
    // ---- early-issue next step's loads (latency hidden under MFMA phase) ----
    float4 nxa, nxb;
    uint4 nwv[6];
    if (kc < 15) {
      const float* gxn = gx + (kc + 1) * 64;
      nxa = *(const float4*)(gxn);
      nxb = *(const float4*)(gxn + 4);
      const unsigned short* gwn = gw + (kc + 1) * 64;
#pragma unroll
      for (int i = 0; i < 6; i++) nwv[i] = *(const uint4*)(gwn + i * 32768);
    }
    // ---- compute current step from LDS[buf] ----
    short8 a0 = *(const short8*)(&XS[buf][l16 * LD + quad * 8]);
    short8 a0h = *(const short8*)(&XS[buf][l16 * LD + 32 + quad * 8]);
    short8 a1 = *(const short8*)(&XS[buf][(16 + l16) * LD + quad * 8]);
    short8 a1h = *(const short8*)(&XS[buf][(16 + l16) * LD + 32 + quad * 8]);
#pragma unroll
    for (int t = 0; t < 3; t++) {
      short8 b0 = *(const short8*)(&WS[buf][(colbase + t * 16 + l16) * LD + quad * 8]);
      short8 b1 = *(const short8*)(&WS[buf][(colbase + t * 16 + l16) * LD + 32 + quad * 8]);
      acc[0][t] = MFMA(a0, b0, acc[0][t]);
      acc[0][t] = MFMA(a0h, b1, acc[0][t]);
      acc[1][t] = MFMA(a1, b0, acc[1][t]);
      acc[1][t] = MFMA(a1h, b1, acc[1][t]);
    }
    // ---- write next step into LDS[buf^1] ----
    if (kc < 15) {
      short8 xc;
      xc[0] = (short)f2bf(nxa.x); xc[1] = (short)f2bf(nxa.y);
      xc[2] = (short)f2bf(nxa.z); xc[3] = (short)f2bf(nxa.w);
      xc[4] = (short)f2bf(nxb.x); xc[5] = (short)f2bf(nxb.y);
      xc[6] = (short)f2bf(nxb.z); xc[7] = (short)f2bf(nxb.w);
      *(short8*)(&XS[buf ^ 1][xr * LD + xj * 8]) = xc;
#pragma unroll
      for (int i = 0; i < 6; i++)
        *(uint4*)(&WS[buf ^ 1][(xr + 32 * i) * LD + xj * 8]) = nwv[i];
    }
    __syncthreads();
  }

  // ---- epilogue: stage per-wave tiles into LDS (aliased), coalesced streams ----
  unsigned short* eQ = &XS[0][0];  // [32][LD]
  unsigned short* eK = &XS[1][0];  // [32][LD]
  unsigned short* eV = &WS[0][0];  // [64][40]
  const int b = row0 >> 12, srow = row0 & 4095;
#pragma unroll
  for (int rt = 0; rt < 2; rt++)
#pragma unroll
    for (int t = 0; t < 3; t++) {
      int col = colbase + t * 16 + l16;
      float bias = bqkv[col];
      int sec = col >> 6, d = col & 63;
#pragma unroll
      for (int r = 0; r < 4; r++) {
        int lrow = rt * 16 + quad * 4 + r;  // 0..31
        float v = acc[rt][t][r] + bias;
        if (sec == 0)      eQ[lrow * LD + d] = f2bf(v * 0.125f);
        else if (sec == 1) eK[lrow * LD + d] = f2bf(v);
        else               eV[d * 40 + lrow] = f2bf(v);  // transpose for V
      }
    }
  __syncthreads();
  {  // coalesced streams: Q,K = 4KB contiguous; V = two 2KB 16-key tiles
    int r = tid >> 3, sg = tid & 7;  // 32 rows x 8 segs of 16 B
    *(uint4*)(Qg + (size_t)(row0 + r) * 64 + sg * 8) = *(const uint4*)(&eQ[r * LD + sg * 8]);
    *(uint4*)(Kg + (size_t)(row0 + r) * 64 + sg * 8) = *(const uint4*)(&eK[r * LD + sg * 8]);
    int tile = tid >> 7, rem = tid & 127, d = rem >> 1, half = rem & 1;
    *(uint4*)(Vtg + (((size_t)b * 256 + (srow >> 4) + tile) * 64 + d) * 16 + half * 8)
        = *(const uint4*)(&eV[d * 40 + tile * 16 + half * 8]);
  }
}

// ---------------- attention partial: block = (qtile, batch, key-split); 1024 keys/split.
// No-max online softmax (scores bounded; Q pre-scaled). Outputs unnormalized O (bf16) + l.
// V^T is tiled: VT[b][key/16][d][16].
__global__ __launch_bounds__(256, 4) void attn_kernel(
    const unsigned short* __restrict__ Qg, const unsigned short* __restrict__ Kg,
    const unsigned short* __restrict__ Vtg,
    unsigned short* __restrict__ Opart, float* __restrict__ Lpart) {
  __shared__ __align__(16) unsigned short Ks[64 * LD];
  __shared__ __align__(16) unsigned short Vs[64 * LD];   // [d][key]
  __shared__ __align__(16) unsigned short QP[64 * LD];   // Q stage, then per-wave P strips

  const int tid = threadIdx.x;
  const int wave = tid >> 6, lane = tid & 63, quad = lane >> 4, l16 = lane & 15;
  const int bid = blockIdx.x;
  const int combo = bid & 15, qt = bid >> 4;   // combo fastest: XCD groups (batch,split)
  const int b = combo >> 2, split = combo & 3;
  const int q0 = qt * 64, key0 = split * 1024;

  {  // Q stage — wave-aligned (tid>>2 spans exactly this wave's 16 rows): no barrier needed
    int r = tid >> 2, seg = tid & 3;
    const uint4* s = (const uint4*)(Qg + ((size_t)b * 4096 + q0 + r) * 64 + seg * 16);
    *(uint4*)(&QP[r * LD + seg * 16])     = s[0];
    *(uint4*)(&QP[r * LD + seg * 16 + 8]) = s[1];
  }
  short8 aq0 = *(const short8*)(&QP[(wave * 16 + l16) * LD + quad * 8]);
  short8 aq1 = *(const short8*)(&QP[(wave * 16 + l16) * LD + 32 + quad * 8]);

  floatx4 o[4];
  float lsum[4];
#pragma unroll
  for (int t = 0; t < 4; t++) o[t] = (floatx4)(0.0f);
#pragma unroll
  for (int r = 0; r < 4; r++) lsum[r] = 0.0f;

  const int kr = tid >> 2, kseg = tid & 3;
  const unsigned short* Kbase = Kg + ((size_t)b * 4096 + key0) * 64;
  const unsigned short* Vt0 = Vtg + ((size_t)b * 256 + (key0 >> 4)) * 1024;  // tile=1024 shorts

  uint4 pk0, pk1, pv0, pv1;
  pk0 = *(const uint4*)(Kbase + (size_t)kr * 64 + kseg * 16);
  pk1 = *(const uint4*)(Kbase + (size_t)kr * 64 + kseg * 16 + 8);
  pv0 = *(const uint4*)(Vt0 + ((size_t)kseg * 64 + kr) * 16);
  pv1 = *(const uint4*)(Vt0 + ((size_t)kseg * 64 + kr) * 16 + 8);

  unsigned short* Pw = &QP[wave * 16 * LD];

  for (int kc = 0; kc < 16; kc++) {
    __syncthreads();
    *(uint4*)(&Ks[kr * LD + kseg * 16])     = pk0;
    *(uint4*)(&Ks[kr * LD + kseg * 16 + 8]) = pk1;
    *(uint4*)(&Vs[kr * LD + kseg * 16])     = pv0;
    *(uint4*)(&Vs[kr * LD + kseg * 16 + 8]) = pv1;
    __syncthreads();
    if (kc < 15) {  // register prefetch of next K/V chunk, overlaps compute
      int nk = (kc + 1) * 64;
      int tl = (kc + 1) * 4 + kseg;  // V tile-local index
      pk0 = *(const uint4*)(Kbase + (size_t)(nk + kr) * 64 + kseg * 16);
      pk1 = *(const uint4*)(Kbase + (size_t)(nk + kr) * 64 + kseg * 16 + 8);
      pv0 = *(const uint4*)(Vt0 + ((size_t)tl * 64 + kr) * 16);
      pv1 = *(const uint4*)(Vt0 + ((size_t)tl * 64 + kr) * 16 + 8);
    }

    floatx4 sc[4];
#pragma unroll
    for (int t = 0; t < 4; t++) sc[t] = (floatx4)(0.0f);
#pragma unroll
    for (int t = 0; t < 4; t++) {
      short8 b0 = *(const short8*)(&Ks[(t * 16 + l16) * LD + quad * 8]);
      short8 b1 = *(const short8*)(&Ks[(t * 16 + l16) * LD + 32 + quad * 8]);
      sc[t] = MFMA(aq0, b0, sc[t]);
      sc[t] = MFMA(aq1, b1, sc[t]);
    }

    // p = exp(s): no max subtraction (|s| bounded), no rescale, l accumulates per-lane
#pragma unroll
    for (int r = 0; r < 4; r++) {
#pragma unroll
      for (int t = 0; t < 4; t++) {
        float pv = __expf(sc[t][r]);
        lsum[r] += pv;
        Pw[(quad * 4 + r) * LD + t * 16 + l16] = f2bf(pv);
      }
    }
    short8 ap0 = *(const short8*)(&Pw[l16 * LD + quad * 8]);
    short8 ap1 = *(const short8*)(&Pw[l16 * LD + 32 + quad * 8]);
#pragma unroll
    for (int t = 0; t < 4; t++) {
      short8 b0 = *(const short8*)(&Vs[(t * 16 + l16) * LD + quad * 8]);
      short8 b1 = *(const short8*)(&Vs[(t * 16 + l16) * LD + 32 + quad * 8]);
      o[t] = MFMA(ap0, b0, o[t]);
      o[t] = MFMA(ap1, b1, o[t]);
    }
  }

  // row-sum of l across the 16-lane col group (cols live in l16; rows in quad)
#pragma unroll
  for (int r = 0; r < 4; r++) {
#pragma unroll
    for (int off = 1; off < 16; off <<= 1) lsum[r] += __shfl_xor(lsum[r], off, 64);
  }

  unsigned short* Ob = Opart + ((size_t)bid * 64 + wave * 16) * 64;
#pragma unroll
  for (int t = 0; t < 4; t++)
#pragma unroll
    for (int r = 0; r < 4; r++)
      Ob[(quad * 4 + r) * 64 + t * 16 + l16] = f2bf(o[t][r]);
  if (l16 == 0) {
#pragma unroll
    for (int r = 0; r < 4; r++)
      Lpart[bid * 64 + wave * 16 + quad * 4 + r] = lsum[r];
  }
}

// ---------------- combine partials + fused out-proj; block = (batch, qtile, e-quarter).
__global__ __launch_bounds__(256, 4) void combine_kernel(
    const unsigned short* __restrict__ Opart, const float* __restrict__ Lpart,
    const unsigned short* __restrict__ WtOut, const float* __restrict__ bout,
    float* __restrict__ out) {
  __shared__ __align__(16) unsigned short Cs[4][16 * LD];
  __shared__ __align__(16) unsigned short Wl[128 * LD];

  const int tid = threadIdx.x;
  const int wave = tid >> 6, lane = tid & 63, quad = lane >> 4, l16 = lane & 15;
  const int cid = blockIdx.x;
  const int eq = cid & 3, qt = (cid >> 2) & 63, b = cid >> 8;
  const int e0 = eq * 256;

  // sum 4 partials; lane owns (q = lane>>2, 16 d starting at (lane&3)*16)
  const int q = lane >> 2, d0 = (lane & 3) * 16;
  float accv[16];
#pragma unroll
  for (int i = 0; i < 16; i++) accv[i] = 0.0f;
  float lq = 0.0f;
#pragma unroll
  for (int s = 0; s < 4; s++) {
    int pid = qt * 16 + b * 4 + s;
    const unsigned short* src = Opart + ((size_t)pid * 64 + wave * 16 + q) * 64 + d0;
    uint4 h0 = *(const uint4*)src;
    uint4 h1 = *(const uint4*)(src + 8);
    const unsigned* hw = (const unsigned*)&h0;
#pragma unroll
    for (int i = 0; i < 4; i++) {
      accv[2 * i]     += asf(hw[i] << 16);
      accv[2 * i + 1] += asf(hw[i] & 0xFFFF0000u);
    }
    const unsigned* hw1 = (const unsigned*)&h1;
#pragma unroll
    for (int i = 0; i < 4; i++) {
      accv[8 + 2 * i]     += asf(hw1[i] << 16);
      accv[8 + 2 * i + 1] += asf(hw1[i] & 0xFFFF0000u);
    }
    lq += Lpart[pid * 64 + wave * 16 + q];
  }
  float inv = 1.0f / lq;
  short8 c0, c1;
#pragma unroll
  for (int i = 0; i < 8; i++) {
    c0[i] = (short)f2bf(accv[i] * inv);
    c1[i] = (short)f2bf(accv[8 + i] * inv);
  }
  *(short8*)(&Cs[wave][q * LD + d0])     = c0;
  *(short8*)(&Cs[wave][q * LD + d0 + 8]) = c1;
  // same-wave LDS round-trip (row q written by lane q*4.. of this wave): no barrier
  short8 ao0 = *(const short8*)(&Cs[wave][l16 * LD + quad * 8]);
  short8 ao1 = *(const short8*)(&Cs[wave][l16 * LD + 32 + quad * 8]);

  const size_t orow0 = (size_t)b * 4096 + qt * 64 + wave * 16;
#pragma unroll 1
  for (int ec = 0; ec < 2; ec++) {
    int ebase = e0 + ec * 128;
    __syncthreads();
    {  // stage 128 rows of WtOut: 2 threads/row, 32 elems (64 B) each
      int er = tid >> 1, half = tid & 1;
      const uint4* s = (const uint4*)(WtOut + (size_t)(ebase + er) * 64 + half * 32);
      uint4 w0 = s[0], w1 = s[1], w2 = s[2], w3 = s[3];
      *(uint4*)(&Wl[er * LD + half * 32])      = w0;
      *(uint4*)(&Wl[er * LD + half * 32 + 8])  = w1;
      *(uint4*)(&Wl[er * LD + half * 32 + 16]) = w2;
      *(uint4*)(&Wl[er * LD + half * 32 + 24]) = w3;
    }
    __syncthreads();
    floatx4 a2[8];
#pragma unroll
    for (int t = 0; t < 8; t++) a2[t] = (floatx4)(0.0f);
#pragma unroll
    for (int t = 0; t < 8; t++) {
      short8 b0 = *(const short8*)(&Wl[(t * 16 + l16) * LD + quad * 8]);
      short8 b1 = *(const short8*)(&Wl[(t * 16 + l16) * LD + 32 + quad * 8]);
      a2[t] = MFMA(ao0, b0, a2[t]);
      a2[t] = MFMA(ao1, b1, a2[t]);
    }
#pragma unroll
    for (int t = 0; t < 8; t++) {
      int e = ebase + t * 16 + l16;
      float bo = bout[e];
#pragma unroll
      for (int r = 0; r < 4; r++)
        out[(orow0 + quad * 4 + r) * 1024 + e] = a2[t][r] + bo;
    }
  }
}

extern "C" void kernel_launch(void* const* d_in, const int* in_sizes, int n_in,
                              void* d_out, int out_size, void* d_ws, size_t ws_size,
                              hipStream_t stream) {
  const float* x    = (const float*)d_in[0];  // [4,4096,1024]
  const float* Wqkv = (const float*)d_in[1];  // [1024,192]
  const float* bqkv = (const float*)d_in[2];  // [192]
  const float* Wout = (const float*)d_in[3];  // [64,1024]
  const float* bout = (const float*)d_in[4];  // [1024]
  float* out = (float*)d_out;                 // [4,4096,1024]

  unsigned short* ws = (unsigned short*)d_ws;
  unsigned short* Qg    = ws;                  // 16384*64 (pre-scaled by 1/8)
  unsigned short* Kg    = Qg + 1048576;        // 16384*64
  unsigned short* Vtg   = Kg + 1048576;        // [4][256][64][16] tiled V^T
  unsigned short* WtQkv = Vtg + 1048576;       // [192][1024]
  unsigned short* WtOut = WtQkv + 196608;      // [1024][64]
  unsigned short* Opart = WtOut + 65536;       // [1024][64][64] bf16 unnormalized
  float*          Lpart = (float*)(Opart + 4194304);  // [1024][64]

  prep_kernel<<<1024, 256, 0, stream>>>(Wqkv, Wout, WtQkv, WtOut);
  qkv_kernel<<<512, 256, 0, stream>>>(x, WtQkv, bqkv, Qg, Kg, Vtg);
  attn_kernel<<<1024, 256, 0, stream>>>(Qg, Kg, Vtg, Opart, Lpart);
  combine_kernel<<<1024, 256, 0, stream>>>(Opart, Lpart, WtOut, bout, out);
}

// Round 6
// 180.467 us; speedup vs baseline: 1.2838x; 1.0217x over previous
//
#include <hip/hip_runtime.h>
#include <hip/hip_bf16.h>

// Fused single-head attention, bf16 MFMA path, flash-decoding split-K.
//   x[4,4096,1024] fp32, W_qkv[1024,192], b_qkv[192], W_out[64,1024], b_out[1024]
//   out[4,4096,1024] fp32
// prep (weights->bf16 transposed) -> qkv GEMM (LDS double-buffer, ONE barrier per
//   K-step; 32 rows/block x 512 blocks; Q pre-scaled 1/8; V^T stored PERMUTED:
//   Vtg[b][g=key/64][d][c=64] with c = pi(k) = (k%16)*4 + k/16)
//   -> attn_partial (4 key-splits, no-max softmax; P packed via v_cvt_pk_bf16_f32
//      and written as ds_write_b64 in pi-order -> conflict-free, 4 writes/lane)
//   -> combine + out-proj (4-way e-split).

#define LD 72  // LDS row stride in bf16 elems: 144 B, 16B-aligned, 4-bank rotate/row

typedef __attribute__((ext_vector_type(8))) short short8;   // 8 bf16 (MFMA A/B frag)
typedef __attribute__((ext_vector_type(4))) short short4v;  // 4 bf16 (8 B)
typedef __attribute__((ext_vector_type(4))) float floatx4;  // MFMA C/D frag

#define MFMA(a, b, c) __builtin_amdgcn_mfma_f32_16x16x32_bf16((a), (b), (c), 0, 0, 0)

__device__ __forceinline__ unsigned short f2bf(float f) {
  union { float f; unsigned u; } c; c.f = f;
  unsigned u = c.u + 0x7fffu + ((c.u >> 16) & 1u);  // RNE
  return (unsigned short)(u >> 16);
}
__device__ __forceinline__ float asf(unsigned u) {
  union { unsigned u; float f; } c; c.u = u; return c.f;
}

// ---------------- prep: WtQkv[n=192][k=1024] = W_qkv[k][n]; WtOut[e=1024][d=64] = W_out[d][e]
__global__ __launch_bounds__(256) void prep_kernel(
    const float* __restrict__ Wqkv, const float* __restrict__ Wout,
    unsigned short* __restrict__ WtQkv, unsigned short* __restrict__ WtOut) {
  int idx = blockIdx.x * 256 + threadIdx.x;
  if (idx < 192 * 1024) {
    int n = idx >> 10, k = idx & 1023;
    WtQkv[idx] = f2bf(Wqkv[k * 192 + n]);
  } else if (idx < 192 * 1024 + 1024 * 64) {
    int j = idx - 192 * 1024;
    int e = j >> 6, d = j & 63;
    WtOut[j] = f2bf(Wout[d * 1024 + e]);
  }
}

// ---------------- QKV: 32 rows/block, 512 blocks (2/CU), LDS double-buffer,
// ONE __syncthreads per K-step. Per step each thread early-issues:
//   x: 2x float4 (32B of one row)  -> cast to 8 bf16 -> 1 ds_write_b128
//   W: 6x uint4 (L2-hot W^T rows)  -> 6 ds_write_b128
// Wave w computes a 32x48 tile (acc[2][3], 12 MFMA/step) from the other buffer.
// Epilogue: Q pre-scaled 1/8; V^T written permuted: group g=key/64, col pi(k).
__global__ __launch_bounds__(256, 2) void qkv_kernel(
    const float* __restrict__ x, const unsigned short* __restrict__ WtQkv,
    const float* __restrict__ bqkv,
    unsigned short* __restrict__ Qg, unsigned short* __restrict__ Kg,
    unsigned short* __restrict__ Vtg) {
  __shared__ __align__(16) unsigned short XS[2][32 * LD];   //  9.2 KB
  __shared__ __align__(16) unsigned short WS[2][192 * LD];  // 55.3 KB

  const int tid = threadIdx.x;
  const int wave = tid >> 6, lane = tid & 63, quad = lane >> 4, l16 = lane & 15;
  const int row0 = blockIdx.x * 32;
  const int colbase = wave * 48;

  floatx4 acc[2][3];
#pragma unroll
  for (int rt = 0; rt < 2; rt++)
#pragma unroll
    for (int t = 0; t < 3; t++) acc[rt][t] = (floatx4)(0.0f);

  // Staging map: thread -> x row xr, 16B-chunk xj; W rows xr+32i (i<6), chunk xj.
  const int xr = tid >> 3, xj = tid & 7;
  const float* gx = x + (size_t)(row0 + xr) * 1024 + xj * 8;
  const unsigned short* gw = WtQkv + (size_t)xr * 1024 + xj * 8;

  {  // prologue: stage step 0 into buffer 0
    float4 xa = *(const float4*)(gx);
    float4 xb = *(const float4*)(gx + 4);
    uint4 wv[6];
#pragma unroll
    for (int i = 0; i < 6; i++) wv[i] = *(const uint4*)(gw + i * 32768);
    short8 xc;
    xc[0] = (short)f2bf(xa.x); xc[1] = (short)f2bf(xa.y);
    xc[2] = (short)f2bf(xa.z); xc[3] = (short)f2bf(xa.w);
    xc[4] = (short)f2bf(xb.x); xc[5] = (short)f2bf(xb.y);
    xc[6] = (short)f2bf(xb.z); xc[7] = (short)f2bf(xb.w);
    *(short8*)(&XS[0][xr * LD + xj * 8]) = xc;
#pragma unroll
    for (int i = 0; i < 6; i++)
      *(uint4*)(&WS[0][(xr + 32 * i) * LD + xj * 8]) = wv[i];
  }
  __syncthreads();

  for (int kc = 0; kc < 16; kc++) {
    const int buf = kc & 1;
    // ---- early-issue next step's loads (latency hidden under MFMA phase) ----
    float4 nxa, nxb;
    uint4 nwv[6];
    if (kc < 15) {
      const float* gxn = gx + (kc + 1) * 64;
      nxa = *(const float4*)(gxn);
      nxb = *(const float4*)(gxn + 4);
      const unsigned short* gwn = gw + (kc + 1) * 64;
#pragma unroll
      for (int i = 0; i < 6; i++) nwv[i] = *(const uint4*)(gwn + i * 32768);
    }
    // ---- compute current step from LDS[buf] ----
    short8 a0 = *(const short8*)(&XS[buf][l16 * LD + quad * 8]);
    short8 a0h = *(const short8*)(&XS[buf][l16 * LD + 32 + quad * 8]);
    short8 a1 = *(const short8*)(&XS[buf][(16 + l16) * LD + quad * 8]);
    short8 a1h = *(const short8*)(&XS[buf][(16 + l16) * LD + 32 + quad * 8]);
#pragma unroll
    for (int t = 0; t < 3; t++) {
      short8 b0 = *(const short8*)(&WS[buf][(colbase + t * 16 + l16) * LD + quad * 8]);
      short8 b1 = *(const short8*)(&WS[buf][(colbase + t * 16 + l16) * LD + 32 + quad * 8]);
      acc[0][t] = MFMA(a0, b0, acc[0][t]);
      acc[0][t] = MFMA(a0h, b1, acc[0][t]);
      acc[1][t] = MFMA(a1, b0, acc[1][t]);
      acc[1][t] = MFMA(a1h, b1, acc[1][t]);
    }
    // ---- write next step into LDS[buf^1] ----
    if (kc < 15) {
      short8 xc;
      xc[0] = (short)f2bf(nxa.x); xc[1] = (short)f2bf(nxa.y);
      xc[2] = (short)f2bf(nxa.z); xc[3] = (short)f2bf(nxa.w);
      xc[4] = (short)f2bf(nxb.x); xc[5] = (short)f2bf(nxb.y);
      xc[6] = (short)f2bf(nxb.z); xc[7] = (short)f2bf(nxb.w);
      *(short8*)(&XS[buf ^ 1][xr * LD + xj * 8]) = xc;
#pragma unroll
      for (int i = 0; i < 6; i++)
        *(uint4*)(&WS[buf ^ 1][(xr + 32 * i) * LD + xj * 8]) = nwv[i];
    }
    __syncthreads();
  }

  // ---- epilogue: stage per-wave tiles into LDS (aliased), coalesced streams ----
  unsigned short* eQ = &XS[0][0];  // [32][LD]
  unsigned short* eK = &XS[1][0];  // [32][LD]
  unsigned short* eV = &WS[0][0];  // [64][40]
  const int b = row0 >> 12, srow = row0 & 4095;
#pragma unroll
  for (int rt = 0; rt < 2; rt++)
#pragma unroll
    for (int t = 0; t < 3; t++) {
      int col = colbase + t * 16 + l16;
      float bias = bqkv[col];
      int sec = col >> 6, d = col & 63;
#pragma unroll
      for (int r = 0; r < 4; r++) {
        int lrow = rt * 16 + quad * 4 + r;  // 0..31
        float v = acc[rt][t][r] + bias;
        if (sec == 0)      eQ[lrow * LD + d] = f2bf(v * 0.125f);
        else if (sec == 1) eK[lrow * LD + d] = f2bf(v);
        else               eV[d * 40 + lrow] = f2bf(v);  // transpose for V
      }
    }
  __syncthreads();
  {  // coalesced streams: Q,K = 4KB contiguous rows
    int r = tid >> 3, sg = tid & 7;  // 32 rows x 8 segs of 16 B
    *(uint4*)(Qg + (size_t)(row0 + r) * 64 + sg * 8) = *(const uint4*)(&eQ[r * LD + sg * 8]);
    *(uint4*)(Kg + (size_t)(row0 + r) * 64 + sg * 8) = *(const uint4*)(&eK[r * LD + sg * 8]);
  }
  {  // V: permuted group layout. Block covers keys j = (srow&63)+lrow, lrow=0..31.
     // c = pi(j) = (j&15)*4 + (j>>4) = (lrow&15)*4 + k0 + (lrow>>4), k0=(srow&63)>>4.
     // Pair (lrow=idx, lrow=idx+16) -> adjacent cols -> one u32 store.
    const int g = srow >> 6, k0 = (srow & 63) >> 4;  // k0 in {0,2}
    int d = tid >> 2, i4 = tid & 3;
    unsigned short* vb = Vtg + (((size_t)b * 64 + g) * 64 + d) * 64 + k0;
#pragma unroll
    for (int ii = 0; ii < 4; ii++) {
      int idx = i4 * 4 + ii;
      unsigned lo = eV[d * 40 + idx];
      unsigned hi = eV[d * 40 + 16 + idx];
      *(unsigned*)(vb + idx * 4) = lo | (hi << 16);
    }
  }
}

// ---------------- attention partial: block = (qtile, batch, key-split); 1024 keys/split.
// No-max online softmax (scores bounded; Q pre-scaled). Outputs unnormalized O (bf16) + l.
// V^T permuted: Vtg[b][g=key/64][d][c=64], c = pi(k). P written in pi-order too, so
// PV contraction is invariant. P pack: v_cvt_pk_bf16_f32 x2 + ds_write_b64 per row.
__global__ __launch_bounds__(256, 4) void attn_kernel(
    const unsigned short* __restrict__ Qg, const unsigned short* __restrict__ Kg,
    const unsigned short* __restrict__ Vtg,
    unsigned short* __restrict__ Opart, float* __restrict__ Lpart) {
  __shared__ __align__(16) unsigned short Ks[64 * LD];
  __shared__ __align__(16) unsigned short Vs[64 * LD];   // [d][c]
  __shared__ __align__(16) unsigned short QP[64 * LD];   // Q stage, then per-wave P strips

  const int tid = threadIdx.x;
  const int wave = tid >> 6, lane = tid & 63, quad = lane >> 4, l16 = lane & 15;
  const int bid = blockIdx.x;
  const int combo = bid & 15, qt = bid >> 4;   // combo fastest: XCD groups (batch,split)
  const int b = combo >> 2, split = combo & 3;
  const int q0 = qt * 64, key0 = split * 1024;

  {  // Q stage — wave-aligned (tid>>2 spans exactly this wave's 16 rows): no barrier needed
    int r = tid >> 2, seg = tid & 3;
    const uint4* s = (const uint4*)(Qg + ((size_t)b * 4096 + q0 + r) * 64 + seg * 16);
    *(uint4*)(&QP[r * LD + seg * 16])     = s[0];
    *(uint4*)(&QP[r * LD + seg * 16 + 8]) = s[1];
  }
  short8 aq0 = *(const short8*)(&QP[(wave * 16 + l16) * LD + quad * 8]);
  short8 aq1 = *(const short8*)(&QP[(wave * 16 + l16) * LD + 32 + quad * 8]);

  floatx4 o[4];
  float lsum[4];
#pragma unroll
  for (int t = 0; t < 4; t++) o[t] = (floatx4)(0.0f);
#pragma unroll
  for (int r = 0; r < 4; r++) lsum[r] = 0.0f;

  const int kr = tid >> 2, kseg = tid & 3;
  const unsigned short* Kbase = Kg + ((size_t)b * 4096 + key0) * 64;
  const unsigned short* Vt0 = Vtg + ((size_t)b * 64 + (key0 >> 6)) * 4096;  // group=4096 shorts

  uint4 pk0, pk1, pv0, pv1;
  pk0 = *(const uint4*)(Kbase + (size_t)kr * 64 + kseg * 16);
  pk1 = *(const uint4*)(Kbase + (size_t)kr * 64 + kseg * 16 + 8);
  pv0 = *(const uint4*)(Vt0 + (size_t)kr * 64 + kseg * 16);
  pv1 = *(const uint4*)(Vt0 + (size_t)kr * 64 + kseg * 16 + 8);

  unsigned short* Pw = &QP[wave * 16 * LD];

  for (int kc = 0; kc < 16; kc++) {
    __syncthreads();
    *(uint4*)(&Ks[kr * LD + kseg * 16])     = pk0;
    *(uint4*)(&Ks[kr * LD + kseg * 16 + 8]) = pk1;
    *(uint4*)(&Vs[kr * LD + kseg * 16])     = pv0;
    *(uint4*)(&Vs[kr * LD + kseg * 16 + 8]) = pv1;
    __syncthreads();
    if (kc < 15) {  // register prefetch of next K/V chunk, overlaps compute
      int nk = (kc + 1) * 64;
      pk0 = *(const uint4*)(Kbase + (size_t)(nk + kr) * 64 + kseg * 16);
      pk1 = *(const uint4*)(Kbase + (size_t)(nk + kr) * 64 + kseg * 16 + 8);
      pv0 = *(const uint4*)(Vt0 + (size_t)(kc + 1) * 4096 + kr * 64 + kseg * 16);
      pv1 = *(const uint4*)(Vt0 + (size_t)(kc + 1) * 4096 + kr * 64 + kseg * 16 + 8);
    }

    floatx4 sc[4];
#pragma unroll
    for (int t = 0; t < 4; t++) sc[t] = (floatx4)(0.0f);
#pragma unroll
    for (int t = 0; t < 4; t++) {
      short8 b0 = *(const short8*)(&Ks[(t * 16 + l16) * LD + quad * 8]);
      short8 b1 = *(const short8*)(&Ks[(t * 16 + l16) * LD + 32 + quad * 8]);
      sc[t] = MFMA(aq0, b0, sc[t]);
      sc[t] = MFMA(aq1, b1, sc[t]);
    }

    // p = exp(s); pack 4 values (cols l16*4+t in pi-order) -> one b64 per row.
#pragma unroll
    for (int r = 0; r < 4; r++) {
      float e0 = __expf(sc[0][r]);
      float e1 = __expf(sc[1][r]);
      float e2 = __expf(sc[2][r]);
      float e3 = __expf(sc[3][r]);
      lsum[r] += (e0 + e1) + (e2 + e3);
      unsigned w0, w1;
      asm("v_cvt_pk_bf16_f32 %0, %1, %2" : "=v"(w0) : "v"(e0), "v"(e1));
      asm("v_cvt_pk_bf16_f32 %0, %1, %2" : "=v"(w1) : "v"(e2), "v"(e3));
      uint2 pw; pw.x = w0; pw.y = w1;
      *(uint2*)(&Pw[(quad * 4 + r) * LD + l16 * 4]) = pw;
    }
    short8 ap0 = *(const short8*)(&Pw[l16 * LD + quad * 8]);
    short8 ap1 = *(const short8*)(&Pw[l16 * LD + 32 + quad * 8]);
#pragma unroll
    for (int t = 0; t < 4; t++) {
      short8 b0 = *(const short8*)(&Vs[(t * 16 + l16) * LD + quad * 8]);
      short8 b1 = *(const short8*)(&Vs[(t * 16 + l16) * LD + 32 + quad * 8]);
      o[t] = MFMA(ap0, b0, o[t]);
      o[t] = MFMA(ap1, b1, o[t]);
    }
  }

  // row-sum of l across the 16-lane col group (cols live in l16; rows in quad)
#pragma unroll
  for (int r = 0; r < 4; r++) {
#pragma unroll
    for (int off = 1; off < 16; off <<= 1) lsum[r] += __shfl_xor(lsum[r], off, 64);
  }

  unsigned short* Ob = Opart + ((size_t)bid * 64 + wave * 16) * 64;
#pragma unroll
  for (int t = 0; t < 4; t++)
#pragma unroll
    for (int r = 0; r < 4; r++)
      Ob[(quad * 4 + r) * 64 + t * 16 + l16] = f2bf(o[t][r]);
  if (l16 == 0) {
#pragma unroll
    for (int r = 0; r < 4; r++)
      Lpart[bid * 64 + wave * 16 + quad * 4 + r] = lsum[r];
  }
}

// ---------------- combine partials + fused out-proj; block = (batch, qtile, e-quarter).
__global__ __launch_bounds__(256, 4) void combine_kernel(
    const unsigned short* __restrict__ Opart, const float* __restrict__ Lpart,
    const unsigned short* __restrict__ WtOut, const float* __restrict__ bout,
    float* __restrict__ out) {
  __shared__ __align__(16) unsigned short Cs[4][16 * LD];
  __shared__ __align__(16) unsigned short Wl[128 * LD];

  const int tid = threadIdx.x;
  const int wave = tid >> 6, lane = tid & 63, quad = lane >> 4, l16 = lane & 15;
  const int cid = blockIdx.x;
  const int eq = cid & 3, qt = (cid >> 2) & 63, b = cid >> 8;
  const int e0 = eq * 256;

  // sum 4 partials; lane owns (q = lane>>2, 16 d starting at (lane&3)*16)
  const int q = lane >> 2, d0 = (lane & 3) * 16;
  float accv[16];
#pragma unroll
  for (int i = 0; i < 16; i++) accv[i] = 0.0f;
  float lq = 0.0f;
#pragma unroll
  for (int s = 0; s < 4; s++) {
    int pid = qt * 16 + b * 4 + s;
    const unsigned short* src = Opart + ((size_t)pid * 64 + wave * 16 + q) * 64 + d0;
    uint4 h0 = *(const uint4*)src;
    uint4 h1 = *(const uint4*)(src + 8);
    const unsigned* hw = (const unsigned*)&h0;
#pragma unroll
    for (int i = 0; i < 4; i++) {
      accv[2 * i]     += asf(hw[i] << 16);
      accv[2 * i + 1] += asf(hw[i] & 0xFFFF0000u);
    }
    const unsigned* hw1 = (const unsigned*)&h1;
#pragma unroll
    for (int i = 0; i < 4; i++) {
      accv[8 + 2 * i]     += asf(hw1[i] << 16);
      accv[8 + 2 * i + 1] += asf(hw1[i] & 0xFFFF0000u);
    }
    lq += Lpart[pid * 64 + wave * 16 + q];
  }
  float inv = 1.0f / lq;
  short8 c0, c1;
#pragma unroll
  for (int i = 0; i < 8; i++) {
    c0[i] = (short)f2bf(accv[i] * inv);
    c1[i] = (short)f2bf(accv[8 + i] * inv);
  }
  *(short8*)(&Cs[wave][q * LD + d0])     = c0;
  *(short8*)(&Cs[wave][q * LD + d0 + 8]) = c1;
  // same-wave LDS round-trip (row q written by lane q*4.. of this wave): no barrier
  short8 ao0 = *(const short8*)(&Cs[wave][l16 * LD + quad * 8]);
  short8 ao1 = *(const short8*)(&Cs[wave][l16 * LD + 32 + quad * 8]);

  const size_t orow0 = (size_t)b * 4096 + qt * 64 + wave * 16;
#pragma unroll 1
  for (int ec = 0; ec < 2; ec++) {
    int ebase = e0 + ec * 128;
    __syncthreads();
    {  // stage 128 rows of WtOut: 2 threads/row, 32 elems (64 B) each
      int er = tid >> 1, half = tid & 1;
      const uint4* s = (const uint4*)(WtOut + (size_t)(ebase + er) * 64 + half * 32);
      uint4 w0 = s[0], w1 = s[1], w2 = s[2], w3 = s[3];
      *(uint4*)(&Wl[er * LD + half * 32])      = w0;
      *(uint4*)(&Wl[er * LD + half * 32 + 8])  = w1;
      *(uint4*)(&Wl[er * LD + half * 32 + 16]) = w2;
      *(uint4*)(&Wl[er * LD + half * 32 + 24]) = w3;
    }
    __syncthreads();
    floatx4 a2[8];
#pragma unroll
    for (int t = 0; t < 8; t++) a2[t] = (floatx4)(0.0f);
#pragma unroll
    for (int t = 0; t < 8; t++) {
      short8 b0 = *(const short8*)(&Wl[(t * 16 + l16) * LD + quad * 8]);
      short8 b1 = *(const short8*)(&Wl[(t * 16 + l16) * LD + 32 + quad * 8]);
      a2[t] = MFMA(ao0, b0, a2[t]);
      a2[t] = MFMA(ao1, b1, a2[t]);
    }
#pragma unroll
    for (int t = 0; t < 8; t++) {
      int e = ebase + t * 16 + l16;
      float bo = bout[e];
#pragma unroll
      for (int r = 0; r < 4; r++)
        out[(orow0 + quad * 4 + r) * 1024 + e] = a2[t][r] + bo;
    }
  }
}

extern "C" void kernel_launch(void* const* d_in, const int* in_sizes, int n_in,
                              void* d_out, int out_size, void* d_ws, size_t ws_size,
                              hipStream_t stream) {
  const float* x    = (const float*)d_in[0];  // [4,4096,1024]
  const float* Wqkv = (const float*)d_in[1];  // [1024,192]
  const float* bqkv = (const float*)d_in[2];  // [192]
  const float* Wout = (const float*)d_in[3];  // [64,1024]
  const float* bout = (const float*)d_in[4];  // [1024]
  float* out = (float*)d_out;                 // [4,4096,1024]

  unsigned short* ws = (unsigned short*)d_ws;
  unsigned short* Qg    = ws;                  // 16384*64 (pre-scaled by 1/8)
  unsigned short* Kg    = Qg + 1048576;        // 16384*64
  unsigned short* Vtg   = Kg + 1048576;        // [4][64 groups][64 d][64 c] pi-permuted V^T
  unsigned short* WtQkv = Vtg + 1048576;       // [192][1024]
  unsigned short* WtOut = WtQkv + 196608;      // [1024][64]
  unsigned short* Opart = WtOut + 65536;       // [1024][64][64] bf16 unnormalized
  float*          Lpart = (float*)(Opart + 4194304);  // [1024][64]

  prep_kernel<<<1024, 256, 0, stream>>>(Wqkv, Wout, WtQkv, WtOut);
  qkv_kernel<<<512, 256, 0, stream>>>(x, WtQkv, bqkv, Qg, Kg, Vtg);
  attn_kernel<<<1024, 256, 0, stream>>>(Qg, Kg, Vtg, Opart, Lpart);
  combine_kernel<<<1024, 256, 0, stream>>>(Opart, Lpart, WtOut, bout, out);
}